// Round 7
// baseline (1090.222 us; speedup 1.0000x reference)
//
#include <hip/hip_runtime.h>
#include <cfloat>
#include <math.h>

// Problem constants
#define BQ 8
#define T 2048
#define D 256
#define DAC 36
#define CH 292
#define K 8192
#define NROWS (BQ*T)          // 16384
#define TAU 1e-3f             // single-bf16-pass error bound (~12 sigma) + np noise
#define FSPLIT 4              // k-splits in fast kernel (512 blocks, 2/CU)
#define NKT 16                // code-tiles (of 128) per block = 2048/128

// Output offsets (floats, reference return order)
#define OFF_IDX   (BQ*CH*T)
#define OFF_CODES (OFF_IDX + NROWS)
#define OFF_LOSS  (OFF_CODES + BQ*DAC*T)
#define OFF_ACQ   (OFF_LOSS + 1)

// ---------------- MFMA-path ws layout, bytes ----------------
#define WN_C2    0                            // float[K]
#define WN_Z2    32768                        // float[NROWS]
#define WN_CNT   98304
#define WN_LIST  98560                        // int[NROWS]
#define WN_LOSS  164096                       // double[512]
#define WN_WIDX  168192                       // int[NROWS]
#define WN_PMX   262144                       // float4[FSPLIT*NROWS] = 1 MB
#define WN_AZ    1310720                      // ushort[16384][256] = 8 MB (hi only)
#define WN_BC    9699328                      // ushort[8192][256]  = 4 MB (hi only)
#define WN_NEED  13893632

// ---------------- old (fallback) ws layout ----------------
#define WS_C2    0
#define WS_Z2    32768
#define WS_PART  131072
#define WS_IDX   655360
#define WS_LOSS  720896
#define MT 32
#define KT 128
#define DC 32
#define NSPLIT 4

typedef float f32x4 __attribute__((ext_vector_type(4)));
typedef __bf16 bf16x8 __attribute__((ext_vector_type(8)));
typedef __attribute__((address_space(1))) const unsigned int gu32;
typedef __attribute__((address_space(3))) unsigned int lu32;

__device__ inline void gl_lds16(const void* gp, void* lp) {
    __builtin_amdgcn_global_load_lds((gu32*)gp, (lu32*)lp, 16, 0, 0);
}

__device__ inline unsigned short f2bf(float x) {   // RNE, finite inputs
    unsigned u = __float_as_uint(x);
    return (unsigned short)((u + 0x7fffu + ((u >> 16) & 1u)) >> 16);
}

__device__ inline void merge3(float& m1, float& m2, int& mi, float o1, float o2, int oi) {
    if (o1 < m1 || (o1 == m1 && oi < mi)) { m2 = fminf(m1, o2); m1 = o1; mi = oi; }
    else                                  { m2 = fminf(m2, o1); }
}

// ---- numpy pairwise-sum emulation (AVX512 W=16, n=256) ----
template <typename F>
__device__ float np_pairwise256_sq(F ld) {
    float S[2];
    #pragma unroll
    for (int h = 0; h < 2; h++) {
        int base = h * 128;
        float v[16];
        #pragma unroll
        for (int l = 0; l < 16; l++) {
            float q[8];
            #pragma unroll
            for (int j = 0; j < 8; j++) { float x = ld(base + j * 16 + l); q[j] = x * x; }
            v[l] = ((q[0] + q[1]) + (q[2] + q[3])) + ((q[4] + q[5]) + (q[6] + q[7]));
        }
        float t1[8], t2[4], t3[2];
        #pragma unroll
        for (int l = 0; l < 8; l++) t1[l] = v[l] + v[l + 8];
        #pragma unroll
        for (int l = 0; l < 4; l++) t2[l] = t1[l] + t1[l + 4];
        t3[0] = t2[0] + t2[2]; t3[1] = t2[1] + t2[3];
        S[h] = t3[0] + t3[1];
    }
    return S[0] + S[1];
}

// fallback-path helpers
__global__ void k_c2pw(const float* __restrict__ cb, float* __restrict__ c2) {
    int k = blockIdx.x * 256 + threadIdx.x;
    const float* row = cb + (size_t)k * D;
    c2[k] = np_pairwise256_sq([&](int d) { return row[d]; });
}

__global__ void k_z2pw(const float* __restrict__ z, float* __restrict__ z2) {
    int n = blockIdx.x * 256 + threadIdx.x;
    int b = n >> 11, t = n & 2047;
    const float* base = z + (size_t)b * CH * T + t;
    z2[n] = np_pairwise256_sq([&](int d) { return base[(size_t)d * T]; });
}

// ------ prep: Az[n][256] = bf16hi(z) + fused z2 (np pairwise) ---------------
__global__ __launch_bounds__(256) void k_prepz(const float* __restrict__ z,
                                               unsigned short* __restrict__ Az,
                                               float* __restrict__ z2) {
    __shared__ float zt[32][260];
    const int tid = threadIdx.x;
    const int b = blockIdx.x >> 6, t0 = (blockIdx.x & 63) * 32;
    for (int i = tid; i < 2048; i += 256) {
        int d = i >> 3, tq = (i & 7) * 4;
        float4 v = *(const float4*)(z + (size_t)(b * CH + d) * T + t0 + tq);
        zt[tq + 0][d] = v.x; zt[tq + 1][d] = v.y;
        zt[tq + 2][d] = v.z; zt[tq + 3][d] = v.w;
    }
    __syncthreads();
    const int t = tid >> 3, c8 = tid & 7;
    unsigned short* rowp = Az + (size_t)(b * 2048 + t0 + t) * 256;
    #pragma unroll
    for (int li = 0; li < 4; li++) {
        int u = c8 + 8 * li;                 // 16B chunk index 0..31
        int dbase = u * 8;
        float f[8];
        *(float4*)&f[0] = *(float4*)&zt[t][dbase];
        *(float4*)&f[4] = *(float4*)&zt[t][dbase + 4];
        unsigned short h[8];
        #pragma unroll
        for (int e = 0; e < 8; e++) h[e] = f2bf(f[e]);
        *(uint4*)(rowp + u * 8) = *(uint4*)h;
    }
    if (tid < 32)
        z2[b * 2048 + t0 + tid] = np_pairwise256_sq([&](int d) { return zt[tid][d]; });
}

// ------ prep: Bc[k][256] = bf16hi(c) + fused c2 + cnt=0 ---------------------
__global__ void k_prepc(const float* __restrict__ cb, unsigned short* __restrict__ Bc,
                        float* __restrict__ c2, int* __restrict__ cnt) {
    __shared__ float crow[4][260];
    const int tid = threadIdx.x, w = tid >> 6, l = tid & 63;
    const int k = blockIdx.x * 4 + w;
    float4 v = *(const float4*)(cb + (size_t)k * D + l * 4);
    *(float4*)&crow[w][l * 4] = v;
    float fa[4] = {v.x, v.y, v.z, v.w};
    unsigned short hi[4];
    #pragma unroll
    for (int e = 0; e < 4; e++) hi[e] = f2bf(fa[e]);
    *(uint2*)(Bc + (size_t)k * 256 + l * 4) = *(uint2*)hi;
    __syncthreads();
    if (tid < 4) {
        int kk = blockIdx.x * 4 + tid;
        c2[kk] = np_pairwise256_sq([&](int d) { return crow[tid][d]; });
    }
    if (blockIdx.x == 0 && tid == 0) *cnt = 0;
}

// ---------------- MFMA fast argmin v4: single bf16 pass (Keff=256) ----------
// Round-5 double-buffered structure (known-good overlap): 128 rows x 2048
// codes per block, 4 staging its per 128-code tile, per-lane running minima.
__global__ __launch_bounds__(256) void k_fast(
        const unsigned short* __restrict__ Az, const unsigned short* __restrict__ Bc,
        const float* __restrict__ c2g, float4* __restrict__ pmx) {
    __shared__ __align__(16) unsigned char smem8[65536];   // 2 x (A 16KB | B 16KB)
    __shared__ float redm1[128], redm2[128];
    __shared__ int   redi[128];

    const int tid = threadIdx.x;
    const int w = tid >> 6, lane = tid & 63;
    const int wm = w >> 1, wn = w & 1;
    const int quad = lane >> 4, c = lane & 15, c7 = c & 7;

    const int sp = blockIdx.x >> 7;          // split 0..3
    const int nt = blockIdx.x & 127;         // row tile
    const int n0 = nt * 128;
    const int kbase = sp * 2048;

    const int srow = lane >> 3;
    const int gsw = (lane & 7) ^ (srow & 7);

    const char* Azb = (const char*)Az;
    const char* Bcb = (const char*)Bc;

    auto stage = [&](int kt, int it, int buf) {
        const int sub = it * 128;            // K sub-slice (bytes), it in 0..3
        const int k0 = kbase + kt * 128;
        unsigned char* base = smem8 + buf * 32768;
        #pragma unroll
        for (int q = 0; q < 4; q++) {
            const int seg = w * 4 + q;
            gl_lds16(Azb + (size_t)(n0 + seg * 8 + srow) * 512 + sub + gsw * 16,
                     base + seg * 1024);
            gl_lds16(Bcb + (size_t)(k0 + seg * 8 + srow) * 512 + sub + gsw * 16,
                     base + 16384 + seg * 1024);
        }
    };

    float bm1[16], bm2[16]; int bid[16];
    #pragma unroll
    for (int sl = 0; sl < 16; sl++) { bm1[sl] = FLT_MAX; bm2[sl] = FLT_MAX; bid[sl] = 0x7fffffff; }

    int cur = 0;
    stage(0, 0, 0);
    for (int kt = 0; kt < NKT; kt++) {
        f32x4 acc[4][4];
        #pragma unroll
        for (int i = 0; i < 4; i++)
            #pragma unroll
            for (int j = 0; j < 4; j++) acc[i][j] = (f32x4)0.0f;

        for (int it = 0; it < 4; it++) {
            __syncthreads();                  // buf[cur] staging complete
            int nit = it + 1, nkt = kt;
            if (nit == 4) { nit = 0; nkt++; }
            if (nkt < NKT) stage(nkt, nit, cur ^ 1);   // prefetch overlaps MFMA
            unsigned char* base = smem8 + cur * 32768;
            #pragma unroll
            for (int s2 = 0; s2 < 2; s2++) {
                const int sw = ((((s2 << 2) | quad) ^ c7) << 4);
                bf16x8 af[4], bfr[4];
                #pragma unroll
                for (int i = 0; i < 4; i++)
                    af[i] = *(const bf16x8*)(base + (wm * 64 + i * 16 + c) * 128 + sw);
                #pragma unroll
                for (int j = 0; j < 4; j++)
                    bfr[j] = *(const bf16x8*)(base + 16384 + (wn * 64 + j * 16 + c) * 128 + sw);
                #pragma unroll
                for (int i = 0; i < 4; i++)
                    #pragma unroll
                    for (int j = 0; j < 4; j++)
                        acc[i][j] = __builtin_amdgcn_mfma_f32_16x16x32_bf16(af[i], bfr[j], acc[i][j], 0, 0, 0);
            }
            cur ^= 1;
        }
        // per-tile register epilogue (k ascending -> strict <, first idx)
        const int ktk = kbase + kt * 128;
        #pragma unroll
        for (int j = 0; j < 4; j++) {
            const int kk = ktk + wn * 64 + j * 16 + c;
            const float c2v = c2g[kk];
            #pragma unroll
            for (int i = 0; i < 4; i++)
                #pragma unroll
                for (int r = 0; r < 4; r++) {
                    float sc = fmaf(-2.0f, acc[i][j][r], c2v);
                    int sl = i * 4 + r;
                    if (sc < bm1[sl]) { bm2[sl] = bm1[sl]; bm1[sl] = sc; bid[sl] = kk; }
                    else if (sc < bm2[sl]) bm2[sl] = sc;
                }
        }
    }

    // once-per-block reduction: butterfly over the 16 c-lanes (same quad)
    #pragma unroll
    for (int mask = 1; mask <= 8; mask <<= 1)
        #pragma unroll
        for (int sl = 0; sl < 16; sl++) {
            float o1 = __shfl_xor(bm1[sl], mask, 64);
            float o2 = __shfl_xor(bm2[sl], mask, 64);
            int   oi = __shfl_xor(bid[sl], mask, 64);
            merge3(bm1[sl], bm2[sl], bid[sl], o1, o2, oi);
        }
    if (c == 0 && wn == 0) {
        #pragma unroll
        for (int i = 0; i < 4; i++)
            #pragma unroll
            for (int r = 0; r < 4; r++) {
                int ml = wm * 64 + i * 16 + quad * 4 + r, sl = i * 4 + r;
                redm1[ml] = bm1[sl]; redm2[ml] = bm2[sl]; redi[ml] = bid[sl];
            }
    }
    __syncthreads();
    if (c == 0 && wn == 1) {
        #pragma unroll
        for (int i = 0; i < 4; i++)
            #pragma unroll
            for (int r = 0; r < 4; r++) {
                int ml = wm * 64 + i * 16 + quad * 4 + r, sl = i * 4 + r;
                merge3(bm1[sl], bm2[sl], bid[sl], redm1[ml], redm2[ml], redi[ml]);
                pmx[(size_t)sp * NROWS + n0 + ml] =
                    make_float4(bm1[sl], bm2[sl], __int_as_float(bid[sl]), 0.f);
            }
    }
}

// ---------------- reduce 4 k-splits; flag ambiguous rows ----------------
__global__ void k_reduce2(const float4* __restrict__ pmx, int* __restrict__ widx,
                          int* __restrict__ cnt, int* __restrict__ list,
                          float* __restrict__ out) {
    int n = blockIdx.x * 256 + threadIdx.x;
    float a1 = FLT_MAX, a2 = FLT_MAX; int ai = 0x7fffffff;
    #pragma unroll
    for (int s = 0; s < FSPLIT; s++) {
        float4 p = pmx[(size_t)s * NROWS + n];
        merge3(a1, a2, ai, p.x, p.y, __float_as_int(p.z));
    }
    widx[n] = ai;
    out[OFF_IDX + n] = (float)ai;
    if (a2 - a1 < TAU) { int pos = atomicAdd(cnt, 1); list[pos] = n; }
}

// -------- exact np-pipeline rescue: 8 rows/block share each codebook pass ---
__global__ __launch_bounds__(256) void k_rescue3(
        const float* __restrict__ z, const float* __restrict__ cb,
        const float* __restrict__ c2, const float* __restrict__ z2,
        const int* __restrict__ cnt, const int* __restrict__ list,
        int* __restrict__ widx, float* __restrict__ out) {
    __shared__ float zrows[8][256];      // 8KB, reads are wave-broadcast
    __shared__ float z2s[8];
    __shared__ int   ns[8];
    __shared__ float rv[256];
    __shared__ int   ri[256];
    const int tid = threadIdx.x;
    const int cntv = *cnt;
    for (int base = blockIdx.x * 8; base < cntv; base += gridDim.x * 8) {
        const int nr = min(8, cntv - base);
        if (tid < 8) {
            int n = list[(tid < nr) ? (base + tid) : base];
            ns[tid] = n; z2s[tid] = z2[n];
        }
        __syncthreads();
        #pragma unroll
        for (int r = 0; r < 8; r++) {
            int n = ns[r];
            zrows[r][tid] = z[(size_t)((n >> 11) * CH + tid) * T + (n & 2047)];
        }
        __syncthreads();
        float bm[8]; int bi[8];
        #pragma unroll
        for (int r = 0; r < 8; r++) { bm[r] = FLT_MAX; bi[r] = 0x7fffffff; }
        for (int j = 0; j < 32; j++) {            // k = tid + 256*j, ascending
            const int k = tid + 256 * j;
            const float4* cr = (const float4*)(cb + (size_t)k * D);
            float e[8];
            #pragma unroll
            for (int r = 0; r < 8; r++) e[r] = 0.f;
            for (int d4 = 0; d4 < 64; d4++) {     // d ascending: BLAS fmaf chain
                float4 cv = cr[d4];
                #pragma unroll
                for (int r = 0; r < 8; r++) {
                    float a = e[r];
                    a = fmaf(zrows[r][d4 * 4 + 0], cv.x, a);
                    a = fmaf(zrows[r][d4 * 4 + 1], cv.y, a);
                    a = fmaf(zrows[r][d4 * 4 + 2], cv.z, a);
                    a = fmaf(zrows[r][d4 * 4 + 3], cv.w, a);
                    e[r] = a;
                }
            }
            const float c2k = c2[k];
            #pragma unroll
            for (int r = 0; r < 8; r++) {
                float s = (z2s[r] - 2.0f * e[r]) + c2k;   // np combine order
                if (s < bm[r]) { bm[r] = s; bi[r] = k; }  // strict <: first idx
            }
        }
        for (int r = 0; r < nr; r++) {
            rv[tid] = bm[r]; ri[tid] = bi[r];
            __syncthreads();
            for (int s = 128; s > 0; s >>= 1) {
                if (tid < s) {
                    float ov = rv[tid + s]; int oi = ri[tid + s];
                    if (ov < rv[tid] || (ov == rv[tid] && oi < ri[tid])) { rv[tid] = ov; ri[tid] = oi; }
                }
                __syncthreads();
            }
            if (tid == 0) { widx[ns[r]] = ri[0]; out[OFF_IDX + ns[r]] = (float)ri[0]; }
            __syncthreads();
        }
    }
}

// ---------------- fallback exact fp32 GEMM-argmin (Round-3, passing) --------
__global__ __launch_bounds__(256) void k_exact(
        const float* __restrict__ z, const float* __restrict__ cb,
        const float* __restrict__ c2, const float* __restrict__ z2,
        float2* __restrict__ part) {
    __shared__ float zs[D][MT];
    __shared__ float cs[DC][KT + 4];
    const int tid = threadIdx.x;
    const int tx = tid & 31, ty = tid >> 5;
    const int n0 = blockIdx.x * MT;
    const int bb = n0 >> 11, t0 = n0 & 2047;
    const int kbase = blockIdx.y * (K / NSPLIT);
    for (int i = tid; i < D * (MT / 4); i += 256) {
        int d = i >> 3, tg = i & 7;
        float4 v = *(const float4*)(z + ((size_t)(bb * CH + d)) * T + t0 + tg * 4);
        *(float4*)&zs[d][tg * 4] = v;
    }
    float z2r[4];
    #pragma unroll
    for (int i = 0; i < 4; i++) z2r[i] = z2[n0 + ty * 4 + i];
    float m1[4]; int bi[4];
    #pragma unroll
    for (int i = 0; i < 4; i++) { m1[i] = FLT_MAX; bi[i] = 0x7fffffff; }
    for (int ktt = 0; ktt < K / NSPLIT; ktt += KT) {
        const int k0 = kbase + ktt;
        float acc[4][4] = {};
        for (int dc = 0; dc < D; dc += DC) {
            __syncthreads();
            {
                int kl = tid & 127, half = tid >> 7;
                const float4* src = (const float4*)(cb + (size_t)(k0 + kl) * D + dc + half * 16);
                #pragma unroll
                for (int j = 0; j < 4; j++) {
                    float4 v = src[j];
                    int dl = half * 16 + j * 4;
                    cs[dl + 0][kl] = v.x; cs[dl + 1][kl] = v.y;
                    cs[dl + 2][kl] = v.z; cs[dl + 3][kl] = v.w;
                }
            }
            __syncthreads();
            #pragma unroll 8
            for (int d = 0; d < DC; d++) {
                const float4 zf = *(const float4*)&zs[dc + d][ty * 4];
                const float4 cf = *(const float4*)&cs[d][tx * 4];
                const float za[4] = {zf.x, zf.y, zf.z, zf.w};
                const float ca[4] = {cf.x, cf.y, cf.z, cf.w};
                #pragma unroll
                for (int i = 0; i < 4; i++)
                    #pragma unroll
                    for (int j = 0; j < 4; j++)
                        acc[i][j] = fmaf(za[i], ca[j], acc[i][j]);
            }
        }
        #pragma unroll
        for (int j = 0; j < 4; j++) {
            int kk = k0 + tx * 4 + j;
            float c2v = c2[kk];
            #pragma unroll
            for (int i = 0; i < 4; i++) {
                float tpre = z2r[i] - 2.0f * acc[i][j];
                float s = tpre + c2v;
                if (s < m1[i]) { m1[i] = s; bi[i] = kk; }
            }
        }
    }
    __syncthreads();
    float* rm1 = (float*)zs;
    int*   rix = (int*)(rm1 + MT * 32);
    #pragma unroll
    for (int i = 0; i < 4; i++) {
        int slot = (ty * 4 + i) * 32 + tx;
        rm1[slot] = m1[i]; rix[slot] = bi[i];
    }
    __syncthreads();
    if (tid < MT) {
        float a1 = FLT_MAX; int ai = 0x7fffffff;
        for (int t = 0; t < 32; t++) {
            float b1 = rm1[tid * 32 + t]; int bidx = rix[tid * 32 + t];
            if (b1 < a1 || (b1 == a1 && bidx < ai)) { a1 = b1; ai = bidx; }
        }
        part[(size_t)(n0 + tid) * NSPLIT + blockIdx.y] = make_float2(a1, __int_as_float(ai));
    }
}

__global__ void k_reduce(const float2* __restrict__ part, int* __restrict__ widx,
                         float* __restrict__ out) {
    int n = blockIdx.x * 256 + threadIdx.x;
    float a1 = FLT_MAX; int ai = 0x7fffffff;
    #pragma unroll
    for (int s = 0; s < NSPLIT; s++) {
        float2 p = part[(size_t)n * NSPLIT + s];
        float b1 = p.x; int bidx = __float_as_int(p.y);
        if (b1 < a1 || (b1 == a1 && bidx < ai)) { a1 = b1; ai = bidx; }
    }
    widx[n] = ai;
    out[OFF_IDX + n] = (float)ai;
}

// ------------- epilogue: gather z_q + loss partials ----------------
__global__ __launch_bounds__(256) void k_episem(
        const float* __restrict__ z, const float* __restrict__ cb,
        const int* __restrict__ widx, float* __restrict__ out, double* __restrict__ lossp) {
    __shared__ int qidx[32];
    __shared__ float qs[32][260];
    __shared__ double wsum[4];
    const int tid = threadIdx.x;
    const int bb = blockIdx.x >> 6;
    const int t0 = (blockIdx.x & 63) * 32;
    if (tid < 32) qidx[tid] = widx[bb * T + t0 + tid];
    __syncthreads();
    for (int i = tid; i < 32 * 64; i += 256) {
        int tl = i >> 6, lanee = i & 63;
        float4 v = *(const float4*)(cb + (size_t)qidx[tl] * D + lanee * 4);
        *(float4*)&qs[tl][lanee * 4] = v;
    }
    __syncthreads();
    double ls = 0.0;
    for (int it = 0; it < 32; it++) {
        int d = it * 8 + (tid >> 5);
        int tl = tid & 31;
        size_t ga = ((size_t)(bb * CH + d)) * T + t0 + tl;
        float q = qs[tl][d];
        float e = q - z[ga];
        out[ga] = q;
        ls += (double)e * (double)e;
    }
    #pragma unroll
    for (int off = 32; off; off >>= 1) ls += __shfl_down(ls, off, 64);
    if ((tid & 63) == 0) wsum[tid >> 6] = ls;
    __syncthreads();
    if (tid == 0) lossp[blockIdx.x] = wsum[0] + wsum[1] + wsum[2] + wsum[3];
}

// ------------- epilogue: ac path + fused loss finalize (block 0) -----------
__global__ void k_epiac(const float* __restrict__ z, const double* __restrict__ lossp,
                        float* __restrict__ out) {
    __shared__ double sm[256];
    int i = (blockIdx.x * 256 + threadIdx.x) * 4;   // grid exact: no early return
    int b = i / (DAC * T);
    int r = i % (DAC * T);
    int d = r / T, t = r % T;
    size_t zoff = ((size_t)(b * CH + 256 + d)) * T + t;
    float4 v = *(const float4*)(z + zoff);
    float r0, r1, r2, r3;
    {
        float t0 = (float)tanh((double)v.x); r0 = rintf(t0 * 10.0f);
        float t1 = (float)tanh((double)v.y); r1 = rintf(t1 * 10.0f);
        float t2 = (float)tanh((double)v.z); r2 = rintf(t2 * 10.0f);
        float t3 = (float)tanh((double)v.w); r3 = rintf(t3 * 10.0f);
    }
    *(float4*)(out + zoff) = make_float4(r0, r1, r2, r3);
    size_t co = OFF_CODES + (size_t)(b * DAC + d) * T + t;
    *(float4*)(out + co) = make_float4(r0 + 10.0f, r1 + 10.0f, r2 + 10.0f, r3 + 10.0f);
    size_t ao = OFF_ACQ + (size_t)(b * DAC + d) * T + t;
    out[ao + 0] = r0; out[ao + 1] = r1; out[ao + 2] = r2; out[ao + 3] = r3;
    if (blockIdx.x == 0) {
        int tid = threadIdx.x;
        sm[tid] = lossp[tid] + lossp[tid + 256];
        __syncthreads();
        for (int off = 128; off; off >>= 1) {
            if (tid < off) sm[tid] += sm[tid + off];
            __syncthreads();
        }
        if (tid == 0) out[OFF_LOSS] = (float)(1.1 * sm[0] / (double)(BQ * D * T));
    }
}

extern "C" void kernel_launch(void* const* d_in, const int* in_sizes, int n_in,
                              void* d_out, int out_size, void* d_ws, size_t ws_size,
                              hipStream_t stream) {
    const float* z  = (const float*)d_in[0];
    const float* cb = (const float*)d_in[1];
    float* out = (float*)d_out;
    char* ws = (char*)d_ws;

    if (ws_size >= (size_t)WN_NEED) {
        float*  c2    = (float*)(ws + WN_C2);
        float*  z2    = (float*)(ws + WN_Z2);
        int*    cnt   = (int*)(ws + WN_CNT);
        int*    list  = (int*)(ws + WN_LIST);
        double* lossp = (double*)(ws + WN_LOSS);
        int*    widx  = (int*)(ws + WN_WIDX);
        float4* pmx   = (float4*)(ws + WN_PMX);
        unsigned short* Az = (unsigned short*)(ws + WN_AZ);
        unsigned short* Bc = (unsigned short*)(ws + WN_BC);

        hipLaunchKernelGGL(k_prepc,   dim3(K / 4),        dim3(256), 0, stream, cb, Bc, c2, cnt);
        hipLaunchKernelGGL(k_prepz,   dim3(512),          dim3(256), 0, stream, z, Az, z2);
        hipLaunchKernelGGL(k_fast,    dim3(128 * FSPLIT), dim3(256), 0, stream, Az, Bc, c2, pmx);
        hipLaunchKernelGGL(k_reduce2, dim3(NROWS / 256),  dim3(256), 0, stream, pmx, widx, cnt, list, out);
        hipLaunchKernelGGL(k_rescue3, dim3(256),          dim3(256), 0, stream, z, cb, c2, z2, cnt, list, widx, out);
        hipLaunchKernelGGL(k_episem,  dim3(BQ * (T / 32)), dim3(256), 0, stream, z, cb, widx, out, lossp);
        hipLaunchKernelGGL(k_epiac,   dim3(BQ * DAC * T / 1024), dim3(256), 0, stream, z, lossp, out);
    } else {
        float*  c2    = (float*)(ws + WS_C2);
        float*  z2    = (float*)(ws + WS_Z2);
        float2* part  = (float2*)(ws + WS_PART);
        int*    widx  = (int*)(ws + WS_IDX);
        double* lossp = (double*)(ws + WS_LOSS);
        hipLaunchKernelGGL(k_c2pw,   dim3(K / 256),            dim3(256), 0, stream, cb, c2);
        hipLaunchKernelGGL(k_z2pw,   dim3(NROWS / 256),        dim3(256), 0, stream, z, z2);
        hipLaunchKernelGGL(k_exact,  dim3(NROWS / MT, NSPLIT), dim3(256), 0, stream, z, cb, c2, z2, part);
        hipLaunchKernelGGL(k_reduce, dim3(NROWS / 256),        dim3(256), 0, stream, part, widx, out);
        hipLaunchKernelGGL(k_episem, dim3(BQ * (T / 32)),      dim3(256), 0, stream, z, cb, widx, out, lossp);
        hipLaunchKernelGGL(k_epiac,  dim3(BQ * DAC * T / 1024), dim3(256), 0, stream, z, lossp, out);
    }
}

// Round 8
// 992.741 us; speedup vs baseline: 1.0982x; 1.0982x over previous
//
#include <hip/hip_runtime.h>
#include <cfloat>
#include <math.h>

// Problem constants
#define BQ 8
#define T 2048
#define D 256
#define DAC 36
#define CH 292
#define K 8192
#define NROWS (BQ*T)          // 16384
#define TAU 1e-3f             // single-bf16-pass error bound + np noise
#define FSPLIT 4              // k-splits in fast kernel
#define NKT 16                // code-tiles (of 128) per block = 2048/128
#define RG 4                  // rows per rescue group

// Output offsets (floats, reference return order)
#define OFF_IDX   (BQ*CH*T)
#define OFF_CODES (OFF_IDX + NROWS)
#define OFF_LOSS  (OFF_CODES + BQ*DAC*T)
#define OFF_ACQ   (OFF_LOSS + 1)

// ---------------- MFMA-path ws layout, bytes ----------------
#define WN_C2    0                            // float[K]
#define WN_Z2    32768                        // float[NROWS]
#define WN_CNT   98304
#define WN_LIST  98560                        // int[NROWS]
#define WN_LOSS  164096                       // double[512]
#define WN_WIDX  168192                       // int[NROWS]
#define WN_PMX   262144                       // float4[FSPLIT*NROWS] = 1 MB
#define WN_AZ    1310720                      // ushort[16384][256] = 8 MB (hi only)
#define WN_BC    9699328                      // ushort[8192][256]  = 4 MB (hi only)
#define WN_PR    13893632                     // float2[4*NROWS] = 512 KB
#define WN_NEED  14417920

// ---------------- old (fallback) ws layout ----------------
#define WS_C2    0
#define WS_Z2    32768
#define WS_PART  131072
#define WS_IDX   655360
#define WS_LOSS  720896
#define MT 32
#define KT 128
#define DC 32
#define NSPLIT 4

typedef float f32x4 __attribute__((ext_vector_type(4)));
typedef __bf16 bf16x8 __attribute__((ext_vector_type(8)));
typedef __attribute__((address_space(1))) const unsigned int gu32;
typedef __attribute__((address_space(3))) unsigned int lu32;

__device__ inline void gl_lds16(const void* gp, void* lp) {
    __builtin_amdgcn_global_load_lds((gu32*)gp, (lu32*)lp, 16, 0, 0);
}

__device__ inline unsigned short f2bf(float x) {   // RNE, finite inputs
    unsigned u = __float_as_uint(x);
    return (unsigned short)((u + 0x7fffu + ((u >> 16) & 1u)) >> 16);
}

__device__ inline void merge3(float& m1, float& m2, int& mi, float o1, float o2, int oi) {
    if (o1 < m1 || (o1 == m1 && oi < mi)) { m2 = fminf(m1, o2); m1 = o1; mi = oi; }
    else                                  { m2 = fminf(m2, o1); }
}

// ---- numpy pairwise-sum emulation (AVX512 W=16, n=256) ----
template <typename F>
__device__ float np_pairwise256_sq(F ld) {
    float S[2];
    #pragma unroll
    for (int h = 0; h < 2; h++) {
        int base = h * 128;
        float v[16];
        #pragma unroll
        for (int l = 0; l < 16; l++) {
            float q[8];
            #pragma unroll
            for (int j = 0; j < 8; j++) { float x = ld(base + j * 16 + l); q[j] = x * x; }
            v[l] = ((q[0] + q[1]) + (q[2] + q[3])) + ((q[4] + q[5]) + (q[6] + q[7]));
        }
        float t1[8], t2[4], t3[2];
        #pragma unroll
        for (int l = 0; l < 8; l++) t1[l] = v[l] + v[l + 8];
        #pragma unroll
        for (int l = 0; l < 4; l++) t2[l] = t1[l] + t1[l + 4];
        t3[0] = t2[0] + t2[2]; t3[1] = t2[1] + t2[3];
        S[h] = t3[0] + t3[1];
    }
    return S[0] + S[1];
}

// fallback-path helpers
__global__ void k_c2pw(const float* __restrict__ cb, float* __restrict__ c2) {
    int k = blockIdx.x * 256 + threadIdx.x;
    const float* row = cb + (size_t)k * D;
    c2[k] = np_pairwise256_sq([&](int d) { return row[d]; });
}

__global__ void k_z2pw(const float* __restrict__ z, float* __restrict__ z2) {
    int n = blockIdx.x * 256 + threadIdx.x;
    int b = n >> 11, t = n & 2047;
    const float* base = z + (size_t)b * CH * T + t;
    z2[n] = np_pairwise256_sq([&](int d) { return base[(size_t)d * T]; });
}

// ------ prep: Az[n][256] = bf16hi(z) + fused z2 (np pairwise) ---------------
__global__ __launch_bounds__(256) void k_prepz(const float* __restrict__ z,
                                               unsigned short* __restrict__ Az,
                                               float* __restrict__ z2) {
    __shared__ float zt[32][260];
    const int tid = threadIdx.x;
    const int b = blockIdx.x >> 6, t0 = (blockIdx.x & 63) * 32;
    for (int i = tid; i < 2048; i += 256) {
        int d = i >> 3, tq = (i & 7) * 4;
        float4 v = *(const float4*)(z + (size_t)(b * CH + d) * T + t0 + tq);
        zt[tq + 0][d] = v.x; zt[tq + 1][d] = v.y;
        zt[tq + 2][d] = v.z; zt[tq + 3][d] = v.w;
    }
    __syncthreads();
    const int t = tid >> 3, c8 = tid & 7;
    unsigned short* rowp = Az + (size_t)(b * 2048 + t0 + t) * 256;
    #pragma unroll
    for (int li = 0; li < 4; li++) {
        int u = c8 + 8 * li;                 // 16B chunk index 0..31
        int dbase = u * 8;
        float f[8];
        *(float4*)&f[0] = *(float4*)&zt[t][dbase];
        *(float4*)&f[4] = *(float4*)&zt[t][dbase + 4];
        unsigned short h[8];
        #pragma unroll
        for (int e = 0; e < 8; e++) h[e] = f2bf(f[e]);
        *(uint4*)(rowp + u * 8) = *(uint4*)h;
    }
    if (tid < 32)
        z2[b * 2048 + t0 + tid] = np_pairwise256_sq([&](int d) { return zt[tid][d]; });
}

// ------ prep: Bc[k][256] = bf16hi(c) + fused c2 + cnt=0 ---------------------
__global__ void k_prepc(const float* __restrict__ cb, unsigned short* __restrict__ Bc,
                        float* __restrict__ c2, int* __restrict__ cnt) {
    __shared__ float crow[4][260];
    const int tid = threadIdx.x, w = tid >> 6, l = tid & 63;
    const int k = blockIdx.x * 4 + w;
    float4 v = *(const float4*)(cb + (size_t)k * D + l * 4);
    *(float4*)&crow[w][l * 4] = v;
    float fa[4] = {v.x, v.y, v.z, v.w};
    unsigned short hi[4];
    #pragma unroll
    for (int e = 0; e < 4; e++) hi[e] = f2bf(fa[e]);
    *(uint2*)(Bc + (size_t)k * 256 + l * 4) = *(uint2*)hi;
    __syncthreads();
    if (tid < 4) {
        int kk = blockIdx.x * 4 + tid;
        c2[kk] = np_pairwise256_sq([&](int d) { return crow[tid][d]; });
    }
    if (blockIdx.x == 0 && tid == 0) *cnt = 0;
}

// ---------------- MFMA fast argmin: single bf16 pass (Keff=256) -------------
__global__ __launch_bounds__(256) void k_fast(
        const unsigned short* __restrict__ Az, const unsigned short* __restrict__ Bc,
        const float* __restrict__ c2g, float4* __restrict__ pmx) {
    __shared__ __align__(16) unsigned char smem8[65536];   // 2 x (A 16KB | B 16KB)
    __shared__ float redm1[128], redm2[128];
    __shared__ int   redi[128];

    const int tid = threadIdx.x;
    const int w = tid >> 6, lane = tid & 63;
    const int wm = w >> 1, wn = w & 1;
    const int quad = lane >> 4, c = lane & 15, c7 = c & 7;

    const int sp = blockIdx.x >> 7;          // split 0..3
    const int nt = blockIdx.x & 127;         // row tile
    const int n0 = nt * 128;
    const int kbase = sp * 2048;

    const int srow = lane >> 3;
    const int gsw = (lane & 7) ^ (srow & 7);

    const char* Azb = (const char*)Az;
    const char* Bcb = (const char*)Bc;

    auto stage = [&](int kt, int it, int buf) {
        const int sub = it * 128;            // K sub-slice (bytes), it in 0..3
        const int k0 = kbase + kt * 128;
        unsigned char* base = smem8 + buf * 32768;
        #pragma unroll
        for (int q = 0; q < 4; q++) {
            const int seg = w * 4 + q;
            gl_lds16(Azb + (size_t)(n0 + seg * 8 + srow) * 512 + sub + gsw * 16,
                     base + seg * 1024);
            gl_lds16(Bcb + (size_t)(k0 + seg * 8 + srow) * 512 + sub + gsw * 16,
                     base + 16384 + seg * 1024);
        }
    };

    float bm1[16], bm2[16]; int bid[16];
    #pragma unroll
    for (int sl = 0; sl < 16; sl++) { bm1[sl] = FLT_MAX; bm2[sl] = FLT_MAX; bid[sl] = 0x7fffffff; }

    int cur = 0;
    stage(0, 0, 0);
    for (int kt = 0; kt < NKT; kt++) {
        f32x4 acc[4][4];
        #pragma unroll
        for (int i = 0; i < 4; i++)
            #pragma unroll
            for (int j = 0; j < 4; j++) acc[i][j] = (f32x4)0.0f;

        for (int it = 0; it < 4; it++) {
            __syncthreads();                  // buf[cur] staging complete
            int nit = it + 1, nkt = kt;
            if (nit == 4) { nit = 0; nkt++; }
            if (nkt < NKT) stage(nkt, nit, cur ^ 1);   // prefetch overlaps MFMA
            unsigned char* base = smem8 + cur * 32768;
            #pragma unroll
            for (int s2 = 0; s2 < 2; s2++) {
                const int sw = ((((s2 << 2) | quad) ^ c7) << 4);
                bf16x8 af[4], bfr[4];
                #pragma unroll
                for (int i = 0; i < 4; i++)
                    af[i] = *(const bf16x8*)(base + (wm * 64 + i * 16 + c) * 128 + sw);
                #pragma unroll
                for (int j = 0; j < 4; j++)
                    bfr[j] = *(const bf16x8*)(base + 16384 + (wn * 64 + j * 16 + c) * 128 + sw);
                #pragma unroll
                for (int i = 0; i < 4; i++)
                    #pragma unroll
                    for (int j = 0; j < 4; j++)
                        acc[i][j] = __builtin_amdgcn_mfma_f32_16x16x32_bf16(af[i], bfr[j], acc[i][j], 0, 0, 0);
            }
            cur ^= 1;
        }
        // per-tile register epilogue (k ascending -> strict <, first idx)
        const int ktk = kbase + kt * 128;
        #pragma unroll
        for (int j = 0; j < 4; j++) {
            const int kk = ktk + wn * 64 + j * 16 + c;
            const float c2v = c2g[kk];
            #pragma unroll
            for (int i = 0; i < 4; i++)
                #pragma unroll
                for (int r = 0; r < 4; r++) {
                    float sc = fmaf(-2.0f, acc[i][j][r], c2v);
                    int sl = i * 4 + r;
                    if (sc < bm1[sl]) { bm2[sl] = bm1[sl]; bm1[sl] = sc; bid[sl] = kk; }
                    else if (sc < bm2[sl]) bm2[sl] = sc;
                }
        }
    }

    // once-per-block reduction: butterfly over the 16 c-lanes (same quad)
    #pragma unroll
    for (int mask = 1; mask <= 8; mask <<= 1)
        #pragma unroll
        for (int sl = 0; sl < 16; sl++) {
            float o1 = __shfl_xor(bm1[sl], mask, 64);
            float o2 = __shfl_xor(bm2[sl], mask, 64);
            int   oi = __shfl_xor(bid[sl], mask, 64);
            merge3(bm1[sl], bm2[sl], bid[sl], o1, o2, oi);
        }
    if (c == 0 && wn == 0) {
        #pragma unroll
        for (int i = 0; i < 4; i++)
            #pragma unroll
            for (int r = 0; r < 4; r++) {
                int ml = wm * 64 + i * 16 + quad * 4 + r, sl = i * 4 + r;
                redm1[ml] = bm1[sl]; redm2[ml] = bm2[sl]; redi[ml] = bid[sl];
            }
    }
    __syncthreads();
    if (c == 0 && wn == 1) {
        #pragma unroll
        for (int i = 0; i < 4; i++)
            #pragma unroll
            for (int r = 0; r < 4; r++) {
                int ml = wm * 64 + i * 16 + quad * 4 + r, sl = i * 4 + r;
                merge3(bm1[sl], bm2[sl], bid[sl], redm1[ml], redm2[ml], redi[ml]);
                pmx[(size_t)sp * NROWS + n0 + ml] =
                    make_float4(bm1[sl], bm2[sl], __int_as_float(bid[sl]), 0.f);
            }
    }
}

// ---------------- reduce 4 k-splits; flag ambiguous rows ----------------
__global__ void k_reduce2(const float4* __restrict__ pmx, int* __restrict__ widx,
                          int* __restrict__ cnt, int* __restrict__ list,
                          float* __restrict__ out) {
    int n = blockIdx.x * 256 + threadIdx.x;
    float a1 = FLT_MAX, a2 = FLT_MAX; int ai = 0x7fffffff;
    #pragma unroll
    for (int s = 0; s < FSPLIT; s++) {
        float4 p = pmx[(size_t)s * NROWS + n];
        merge3(a1, a2, ai, p.x, p.y, __float_as_int(p.z));
    }
    widx[n] = ai;
    out[OFF_IDX + n] = (float)ai;
    if (a2 - a1 < TAU) { int pos = atomicAdd(cnt, 1); list[pos] = n; }
}

// -------- exact np-pipeline rescue v4: (4 rows) x (2048-code split) blocks --
// d4-outer loop: z read from LDS once per d4 (64x fewer LDS reads than v3),
// codebook prefetched one d4 ahead. Chain per (row,k) stays d-ascending fmaf.
__global__ __launch_bounds__(256) void k_rescue4(
        const float* __restrict__ z, const float* __restrict__ cb,
        const float* __restrict__ c2, const float* __restrict__ z2,
        const int* __restrict__ cnt, const int* __restrict__ list,
        float2* __restrict__ pr) {
    __shared__ float zrows[RG][256];
    __shared__ float z2s[RG];
    __shared__ int   ns[RG];
    __shared__ float rv[256];
    __shared__ int   ri[256];
    const int tid = threadIdx.x;
    const int sp = blockIdx.x & 3;
    const int grp0 = blockIdx.x >> 2;        // 0..511
    const int kb = sp * 2048;
    const int cntv = *cnt;

    // hoisted per-thread codebook row pointers (k = kb + tid + 256*j)
    const float4* cr[8];
    #pragma unroll
    for (int j = 0; j < 8; j++)
        cr[j] = (const float4*)(cb + (size_t)(kb + tid + 256 * j) * D);
    float c2r[8];
    #pragma unroll
    for (int j = 0; j < 8; j++) c2r[j] = c2[kb + tid + 256 * j];

    for (int g = grp0; g * RG < cntv; g += 512) {
        const int base = g * RG;
        const int nr = min(RG, cntv - base);
        if (tid < RG) {
            int n = list[base + ((tid < nr) ? tid : 0)];
            ns[tid] = n; z2s[tid] = z2[n];
        }
        __syncthreads();
        #pragma unroll
        for (int r = 0; r < RG; r++) {
            int n = ns[r];
            zrows[r][tid] = z[(size_t)((n >> 11) * CH + tid) * T + (n & 2047)];
        }
        __syncthreads();

        float acc[8][RG];
        #pragma unroll
        for (int j = 0; j < 8; j++)
            #pragma unroll
            for (int r = 0; r < RG; r++) acc[j][r] = 0.f;

        float4 cbuf[8];
        #pragma unroll
        for (int j = 0; j < 8; j++) cbuf[j] = cr[j][0];
        for (int d4 = 0; d4 < 64; d4++) {
            float4 znow[RG];
            #pragma unroll
            for (int r = 0; r < RG; r++) znow[r] = *(const float4*)&zrows[r][d4 * 4];
            float4 cnow[8];
            #pragma unroll
            for (int j = 0; j < 8; j++) cnow[j] = cbuf[j];
            if (d4 < 63) {
                #pragma unroll
                for (int j = 0; j < 8; j++) cbuf[j] = cr[j][d4 + 1];  // prefetch
            }
            #pragma unroll
            for (int j = 0; j < 8; j++)
                #pragma unroll
                for (int r = 0; r < RG; r++) {
                    float a = acc[j][r];
                    a = fmaf(znow[r].x, cnow[j].x, a);   // d ascending: BLAS chain
                    a = fmaf(znow[r].y, cnow[j].y, a);
                    a = fmaf(znow[r].z, cnow[j].z, a);
                    a = fmaf(znow[r].w, cnow[j].w, a);
                    acc[j][r] = a;
                }
        }

        #pragma unroll
        for (int r = 0; r < RG; r++) {
            float bm = FLT_MAX; int bi = 0x7fffffff;
            #pragma unroll
            for (int j = 0; j < 8; j++) {                 // j ascending = k ascending
                float s = (z2s[r] - 2.0f * acc[j][r]) + c2r[j];   // np combine order
                if (s < bm) { bm = s; bi = kb + tid + 256 * j; }
            }
            rv[tid] = bm; ri[tid] = bi;
            __syncthreads();
            for (int s = 128; s > 0; s >>= 1) {
                if (tid < s) {
                    float ov = rv[tid + s]; int oi = ri[tid + s];
                    if (ov < rv[tid] || (ov == rv[tid] && oi < ri[tid])) { rv[tid] = ov; ri[tid] = oi; }
                }
                __syncthreads();
            }
            if (tid == 0 && r < nr)
                pr[(size_t)sp * NROWS + base + r] = make_float2(rv[0], __int_as_float(ri[0]));
            __syncthreads();
        }
    }
}

// -------- merge rescue splits (deterministic, split-ascending) --------------
__global__ void k_unpack(const float2* __restrict__ pr, const int* __restrict__ cnt,
                         const int* __restrict__ list, int* __restrict__ widx,
                         float* __restrict__ out) {
    int pos = blockIdx.x * 256 + threadIdx.x;
    if (pos >= *cnt) return;
    float a1 = FLT_MAX; int ai = 0x7fffffff;
    #pragma unroll
    for (int s = 0; s < 4; s++) {
        float2 p = pr[(size_t)s * NROWS + pos];
        float v = p.x; int ix = __float_as_int(p.y);
        if (v < a1 || (v == a1 && ix < ai)) { a1 = v; ai = ix; }
    }
    int n = list[pos];
    widx[n] = ai;
    out[OFF_IDX + n] = (float)ai;
}

// ---------------- fallback exact fp32 GEMM-argmin (Round-3, passing) --------
__global__ __launch_bounds__(256) void k_exact(
        const float* __restrict__ z, const float* __restrict__ cb,
        const float* __restrict__ c2, const float* __restrict__ z2,
        float2* __restrict__ part) {
    __shared__ float zs[D][MT];
    __shared__ float cs[DC][KT + 4];
    const int tid = threadIdx.x;
    const int tx = tid & 31, ty = tid >> 5;
    const int n0 = blockIdx.x * MT;
    const int bb = n0 >> 11, t0 = n0 & 2047;
    const int kbase = blockIdx.y * (K / NSPLIT);
    for (int i = tid; i < D * (MT / 4); i += 256) {
        int d = i >> 3, tg = i & 7;
        float4 v = *(const float4*)(z + ((size_t)(bb * CH + d)) * T + t0 + tg * 4);
        *(float4*)&zs[d][tg * 4] = v;
    }
    float z2r[4];
    #pragma unroll
    for (int i = 0; i < 4; i++) z2r[i] = z2[n0 + ty * 4 + i];
    float m1[4]; int bi[4];
    #pragma unroll
    for (int i = 0; i < 4; i++) { m1[i] = FLT_MAX; bi[i] = 0x7fffffff; }
    for (int ktt = 0; ktt < K / NSPLIT; ktt += KT) {
        const int k0 = kbase + ktt;
        float acc[4][4] = {};
        for (int dc = 0; dc < D; dc += DC) {
            __syncthreads();
            {
                int kl = tid & 127, half = tid >> 7;
                const float4* src = (const float4*)(cb + (size_t)(k0 + kl) * D + dc + half * 16);
                #pragma unroll
                for (int j = 0; j < 4; j++) {
                    float4 v = src[j];
                    int dl = half * 16 + j * 4;
                    cs[dl + 0][kl] = v.x; cs[dl + 1][kl] = v.y;
                    cs[dl + 2][kl] = v.z; cs[dl + 3][kl] = v.w;
                }
            }
            __syncthreads();
            #pragma unroll 8
            for (int d = 0; d < DC; d++) {
                const float4 zf = *(const float4*)&zs[dc + d][ty * 4];
                const float4 cf = *(const float4*)&cs[d][tx * 4];
                const float za[4] = {zf.x, zf.y, zf.z, zf.w};
                const float ca[4] = {cf.x, cf.y, cf.z, cf.w};
                #pragma unroll
                for (int i = 0; i < 4; i++)
                    #pragma unroll
                    for (int j = 0; j < 4; j++)
                        acc[i][j] = fmaf(za[i], ca[j], acc[i][j]);
            }
        }
        #pragma unroll
        for (int j = 0; j < 4; j++) {
            int kk = k0 + tx * 4 + j;
            float c2v = c2[kk];
            #pragma unroll
            for (int i = 0; i < 4; i++) {
                float tpre = z2r[i] - 2.0f * acc[i][j];
                float s = tpre + c2v;
                if (s < m1[i]) { m1[i] = s; bi[i] = kk; }
            }
        }
    }
    __syncthreads();
    float* rm1 = (float*)zs;
    int*   rix = (int*)(rm1 + MT * 32);
    #pragma unroll
    for (int i = 0; i < 4; i++) {
        int slot = (ty * 4 + i) * 32 + tx;
        rm1[slot] = m1[i]; rix[slot] = bi[i];
    }
    __syncthreads();
    if (tid < MT) {
        float a1 = FLT_MAX; int ai = 0x7fffffff;
        for (int t = 0; t < 32; t++) {
            float b1 = rm1[tid * 32 + t]; int bidx = rix[tid * 32 + t];
            if (b1 < a1 || (b1 == a1 && bidx < ai)) { a1 = b1; ai = bidx; }
        }
        part[(size_t)(n0 + tid) * NSPLIT + blockIdx.y] = make_float2(a1, __int_as_float(ai));
    }
}

__global__ void k_reduce(const float2* __restrict__ part, int* __restrict__ widx,
                         float* __restrict__ out) {
    int n = blockIdx.x * 256 + threadIdx.x;
    float a1 = FLT_MAX; int ai = 0x7fffffff;
    #pragma unroll
    for (int s = 0; s < NSPLIT; s++) {
        float2 p = part[(size_t)n * NSPLIT + s];
        float b1 = p.x; int bidx = __float_as_int(p.y);
        if (b1 < a1 || (b1 == a1 && bidx < ai)) { a1 = b1; ai = bidx; }
    }
    widx[n] = ai;
    out[OFF_IDX + n] = (float)ai;
}

// ------------- epilogue: gather z_q + loss partials ----------------
__global__ __launch_bounds__(256) void k_episem(
        const float* __restrict__ z, const float* __restrict__ cb,
        const int* __restrict__ widx, float* __restrict__ out, double* __restrict__ lossp) {
    __shared__ int qidx[32];
    __shared__ float qs[32][260];
    __shared__ double wsum[4];
    const int tid = threadIdx.x;
    const int bb = blockIdx.x >> 6;
    const int t0 = (blockIdx.x & 63) * 32;
    if (tid < 32) qidx[tid] = widx[bb * T + t0 + tid];
    __syncthreads();
    for (int i = tid; i < 32 * 64; i += 256) {
        int tl = i >> 6, lanee = i & 63;
        float4 v = *(const float4*)(cb + (size_t)qidx[tl] * D + lanee * 4);
        *(float4*)&qs[tl][lanee * 4] = v;
    }
    __syncthreads();
    double ls = 0.0;
    for (int it = 0; it < 32; it++) {
        int d = it * 8 + (tid >> 5);
        int tl = tid & 31;
        size_t ga = ((size_t)(bb * CH + d)) * T + t0 + tl;
        float q = qs[tl][d];
        float e = q - z[ga];
        out[ga] = q;
        ls += (double)e * (double)e;
    }
    #pragma unroll
    for (int off = 32; off; off >>= 1) ls += __shfl_down(ls, off, 64);
    if ((tid & 63) == 0) wsum[tid >> 6] = ls;
    __syncthreads();
    if (tid == 0) lossp[blockIdx.x] = wsum[0] + wsum[1] + wsum[2] + wsum[3];
}

// ------------- epilogue: ac path + fused loss finalize (block 0) -----------
__global__ void k_epiac(const float* __restrict__ z, const double* __restrict__ lossp,
                        float* __restrict__ out) {
    __shared__ double sm[256];
    int i = (blockIdx.x * 256 + threadIdx.x) * 4;   // grid exact: no early return
    int b = i / (DAC * T);
    int r = i % (DAC * T);
    int d = r / T, t = r % T;
    size_t zoff = ((size_t)(b * CH + 256 + d)) * T + t;
    float4 v = *(const float4*)(z + zoff);
    float r0, r1, r2, r3;
    {
        float t0 = (float)tanh((double)v.x); r0 = rintf(t0 * 10.0f);
        float t1 = (float)tanh((double)v.y); r1 = rintf(t1 * 10.0f);
        float t2 = (float)tanh((double)v.z); r2 = rintf(t2 * 10.0f);
        float t3 = (float)tanh((double)v.w); r3 = rintf(t3 * 10.0f);
    }
    *(float4*)(out + zoff) = make_float4(r0, r1, r2, r3);
    size_t co = OFF_CODES + (size_t)(b * DAC + d) * T + t;
    *(float4*)(out + co) = make_float4(r0 + 10.0f, r1 + 10.0f, r2 + 10.0f, r3 + 10.0f);
    size_t ao = OFF_ACQ + (size_t)(b * DAC + d) * T + t;
    out[ao + 0] = r0; out[ao + 1] = r1; out[ao + 2] = r2; out[ao + 3] = r3;
    if (blockIdx.x == 0) {
        int tid = threadIdx.x;
        sm[tid] = lossp[tid] + lossp[tid + 256];
        __syncthreads();
        for (int off = 128; off; off >>= 1) {
            if (tid < off) sm[tid] += sm[tid + off];
            __syncthreads();
        }
        if (tid == 0) out[OFF_LOSS] = (float)(1.1 * sm[0] / (double)(BQ * D * T));
    }
}

extern "C" void kernel_launch(void* const* d_in, const int* in_sizes, int n_in,
                              void* d_out, int out_size, void* d_ws, size_t ws_size,
                              hipStream_t stream) {
    const float* z  = (const float*)d_in[0];
    const float* cb = (const float*)d_in[1];
    float* out = (float*)d_out;
    char* ws = (char*)d_ws;

    if (ws_size >= (size_t)WN_NEED) {
        float*  c2    = (float*)(ws + WN_C2);
        float*  z2    = (float*)(ws + WN_Z2);
        int*    cnt   = (int*)(ws + WN_CNT);
        int*    list  = (int*)(ws + WN_LIST);
        double* lossp = (double*)(ws + WN_LOSS);
        int*    widx  = (int*)(ws + WN_WIDX);
        float4* pmx   = (float4*)(ws + WN_PMX);
        unsigned short* Az = (unsigned short*)(ws + WN_AZ);
        unsigned short* Bc = (unsigned short*)(ws + WN_BC);
        float2* pr    = (float2*)(ws + WN_PR);

        hipLaunchKernelGGL(k_prepc,   dim3(K / 4),        dim3(256), 0, stream, cb, Bc, c2, cnt);
        hipLaunchKernelGGL(k_prepz,   dim3(512),          dim3(256), 0, stream, z, Az, z2);
        hipLaunchKernelGGL(k_fast,    dim3(128 * FSPLIT), dim3(256), 0, stream, Az, Bc, c2, pmx);
        hipLaunchKernelGGL(k_reduce2, dim3(NROWS / 256),  dim3(256), 0, stream, pmx, widx, cnt, list, out);
        hipLaunchKernelGGL(k_rescue4, dim3(2048),         dim3(256), 0, stream, z, cb, c2, z2, cnt, list, pr);
        hipLaunchKernelGGL(k_unpack,  dim3(NROWS / 256),  dim3(256), 0, stream, pr, cnt, list, widx, out);
        hipLaunchKernelGGL(k_episem,  dim3(BQ * (T / 32)), dim3(256), 0, stream, z, cb, widx, out, lossp);
        hipLaunchKernelGGL(k_epiac,   dim3(BQ * DAC * T / 1024), dim3(256), 0, stream, z, lossp, out);
    } else {
        float*  c2    = (float*)(ws + WS_C2);
        float*  z2    = (float*)(ws + WS_Z2);
        float2* part  = (float2*)(ws + WS_PART);
        int*    widx  = (int*)(ws + WS_IDX);
        double* lossp = (double*)(ws + WS_LOSS);
        hipLaunchKernelGGL(k_c2pw,   dim3(K / 256),            dim3(256), 0, stream, cb, c2);
        hipLaunchKernelGGL(k_z2pw,   dim3(NROWS / 256),        dim3(256), 0, stream, z, z2);
        hipLaunchKernelGGL(k_exact,  dim3(NROWS / MT, NSPLIT), dim3(256), 0, stream, z, cb, c2, z2, part);
        hipLaunchKernelGGL(k_reduce, dim3(NROWS / 256),        dim3(256), 0, stream, part, widx, out);
        hipLaunchKernelGGL(k_episem, dim3(BQ * (T / 32)),      dim3(256), 0, stream, z, cb, widx, out, lossp);
        hipLaunchKernelGGL(k_epiac,  dim3(BQ * DAC * T / 1024), dim3(256), 0, stream, z, lossp, out);
    }
}

// Round 9
// 687.449 us; speedup vs baseline: 1.5859x; 1.4441x over previous
//
#include <hip/hip_runtime.h>
#include <cfloat>
#include <math.h>

// Problem constants
#define BQ 8
#define T 2048
#define D 256
#define DAC 36
#define CH 292
#define K 8192
#define NROWS (BQ*T)          // 16384
#define TAU 1e-3f             // single-bf16-pass error bound + np noise
#define FSPLIT 4              // k-splits in fast kernel
#define NKT 16                // code-tiles (of 128) per block = 2048/128
#define RSPLIT 8              // k-splits in rescue (1024 codes each)

// Output offsets (floats, reference return order)
#define OFF_IDX   (BQ*CH*T)
#define OFF_CODES (OFF_IDX + NROWS)
#define OFF_LOSS  (OFF_CODES + BQ*DAC*T)
#define OFF_ACQ   (OFF_LOSS + 1)

// ---------------- MFMA-path ws layout, bytes ----------------
#define WN_C2    0                            // float[K]
#define WN_Z2    32768                        // float[NROWS]
#define WN_CNT   98304
#define WN_LIST  98560                        // int[NROWS]
#define WN_LOSS  164096                       // double[512]
#define WN_WIDX  168192                       // int[NROWS]
#define WN_PMX   262144                       // float4[FSPLIT*NROWS] = 1 MB
#define WN_AZ    1310720                      // ushort[16384][256] = 8 MB (hi only)
#define WN_BC    9699328                      // ushort[8192][256]  = 4 MB (hi only)
#define WN_PR    13893632                     // float2[RSPLIT*NROWS] = 2 MB
#define WN_NEED  15990784

// ---------------- old (fallback) ws layout ----------------
#define WS_C2    0
#define WS_Z2    32768
#define WS_PART  131072
#define WS_IDX   655360
#define WS_LOSS  720896
#define MT 32
#define KT 128
#define DC 32
#define NSPLIT 4

typedef float f32x4 __attribute__((ext_vector_type(4)));
typedef __bf16 bf16x8 __attribute__((ext_vector_type(8)));
typedef __attribute__((address_space(1))) const unsigned int gu32;
typedef __attribute__((address_space(3))) unsigned int lu32;

__device__ inline void gl_lds16(const void* gp, void* lp) {
    __builtin_amdgcn_global_load_lds((gu32*)gp, (lu32*)lp, 16, 0, 0);
}

__device__ inline unsigned short f2bf(float x) {   // RNE, finite inputs
    unsigned u = __float_as_uint(x);
    return (unsigned short)((u + 0x7fffu + ((u >> 16) & 1u)) >> 16);
}

__device__ inline void merge3(float& m1, float& m2, int& mi, float o1, float o2, int oi) {
    if (o1 < m1 || (o1 == m1 && oi < mi)) { m2 = fminf(m1, o2); m1 = o1; mi = oi; }
    else                                  { m2 = fminf(m2, o1); }
}

// ---- numpy pairwise-sum emulation (AVX512 W=16, n=256) ----
template <typename F>
__device__ float np_pairwise256_sq(F ld) {
    float S[2];
    #pragma unroll
    for (int h = 0; h < 2; h++) {
        int base = h * 128;
        float v[16];
        #pragma unroll
        for (int l = 0; l < 16; l++) {
            float q[8];
            #pragma unroll
            for (int j = 0; j < 8; j++) { float x = ld(base + j * 16 + l); q[j] = x * x; }
            v[l] = ((q[0] + q[1]) + (q[2] + q[3])) + ((q[4] + q[5]) + (q[6] + q[7]));
        }
        float t1[8], t2[4], t3[2];
        #pragma unroll
        for (int l = 0; l < 8; l++) t1[l] = v[l] + v[l + 8];
        #pragma unroll
        for (int l = 0; l < 4; l++) t2[l] = t1[l] + t1[l + 4];
        t3[0] = t2[0] + t2[2]; t3[1] = t2[1] + t2[3];
        S[h] = t3[0] + t3[1];
    }
    return S[0] + S[1];
}

// fallback-path helpers
__global__ void k_c2pw(const float* __restrict__ cb, float* __restrict__ c2) {
    int k = blockIdx.x * 256 + threadIdx.x;
    const float* row = cb + (size_t)k * D;
    c2[k] = np_pairwise256_sq([&](int d) { return row[d]; });
}

__global__ void k_z2pw(const float* __restrict__ z, float* __restrict__ z2) {
    int n = blockIdx.x * 256 + threadIdx.x;
    int b = n >> 11, t = n & 2047;
    const float* base = z + (size_t)b * CH * T + t;
    z2[n] = np_pairwise256_sq([&](int d) { return base[(size_t)d * T]; });
}

// ------ prep: Az[n][256] = bf16hi(z) + fused z2 (np pairwise) ---------------
__global__ __launch_bounds__(256) void k_prepz(const float* __restrict__ z,
                                               unsigned short* __restrict__ Az,
                                               float* __restrict__ z2) {
    __shared__ float zt[32][260];
    const int tid = threadIdx.x;
    const int b = blockIdx.x >> 6, t0 = (blockIdx.x & 63) * 32;
    for (int i = tid; i < 2048; i += 256) {
        int d = i >> 3, tq = (i & 7) * 4;
        float4 v = *(const float4*)(z + (size_t)(b * CH + d) * T + t0 + tq);
        zt[tq + 0][d] = v.x; zt[tq + 1][d] = v.y;
        zt[tq + 2][d] = v.z; zt[tq + 3][d] = v.w;
    }
    __syncthreads();
    const int t = tid >> 3, c8 = tid & 7;
    unsigned short* rowp = Az + (size_t)(b * 2048 + t0 + t) * 256;
    #pragma unroll
    for (int li = 0; li < 4; li++) {
        int u = c8 + 8 * li;                 // 16B chunk index 0..31
        int dbase = u * 8;
        float f[8];
        *(float4*)&f[0] = *(float4*)&zt[t][dbase];
        *(float4*)&f[4] = *(float4*)&zt[t][dbase + 4];
        unsigned short h[8];
        #pragma unroll
        for (int e = 0; e < 8; e++) h[e] = f2bf(f[e]);
        *(uint4*)(rowp + u * 8) = *(uint4*)h;
    }
    if (tid < 32)
        z2[b * 2048 + t0 + tid] = np_pairwise256_sq([&](int d) { return zt[tid][d]; });
}

// ------ prep: Bc[k][256] = bf16hi(c) + fused c2 + cnt=0 ---------------------
__global__ void k_prepc(const float* __restrict__ cb, unsigned short* __restrict__ Bc,
                        float* __restrict__ c2, int* __restrict__ cnt) {
    __shared__ float crow[4][260];
    const int tid = threadIdx.x, w = tid >> 6, l = tid & 63;
    const int k = blockIdx.x * 4 + w;
    float4 v = *(const float4*)(cb + (size_t)k * D + l * 4);
    *(float4*)&crow[w][l * 4] = v;
    float fa[4] = {v.x, v.y, v.z, v.w};
    unsigned short hi[4];
    #pragma unroll
    for (int e = 0; e < 4; e++) hi[e] = f2bf(fa[e]);
    *(uint2*)(Bc + (size_t)k * 256 + l * 4) = *(uint2*)hi;
    __syncthreads();
    if (tid < 4) {
        int kk = blockIdx.x * 4 + tid;
        c2[kk] = np_pairwise256_sq([&](int d) { return crow[tid][d]; });
    }
    if (blockIdx.x == 0 && tid == 0) *cnt = 0;
}

// ---------------- MFMA fast argmin: single bf16 pass (Keff=256) -------------
__global__ __launch_bounds__(256) void k_fast(
        const unsigned short* __restrict__ Az, const unsigned short* __restrict__ Bc,
        const float* __restrict__ c2g, float4* __restrict__ pmx) {
    __shared__ __align__(16) unsigned char smem8[65536];   // 2 x (A 16KB | B 16KB)
    __shared__ float redm1[128], redm2[128];
    __shared__ int   redi[128];

    const int tid = threadIdx.x;
    const int w = tid >> 6, lane = tid & 63;
    const int wm = w >> 1, wn = w & 1;
    const int quad = lane >> 4, c = lane & 15, c7 = c & 7;

    const int sp = blockIdx.x >> 7;          // split 0..3
    const int nt = blockIdx.x & 127;         // row tile
    const int n0 = nt * 128;
    const int kbase = sp * 2048;

    const int srow = lane >> 3;
    const int gsw = (lane & 7) ^ (srow & 7);

    const char* Azb = (const char*)Az;
    const char* Bcb = (const char*)Bc;

    auto stage = [&](int kt, int it, int buf) {
        const int sub = it * 128;            // K sub-slice (bytes), it in 0..3
        const int k0 = kbase + kt * 128;
        unsigned char* base = smem8 + buf * 32768;
        #pragma unroll
        for (int q = 0; q < 4; q++) {
            const int seg = w * 4 + q;
            gl_lds16(Azb + (size_t)(n0 + seg * 8 + srow) * 512 + sub + gsw * 16,
                     base + seg * 1024);
            gl_lds16(Bcb + (size_t)(k0 + seg * 8 + srow) * 512 + sub + gsw * 16,
                     base + 16384 + seg * 1024);
        }
    };

    float bm1[16], bm2[16]; int bid[16];
    #pragma unroll
    for (int sl = 0; sl < 16; sl++) { bm1[sl] = FLT_MAX; bm2[sl] = FLT_MAX; bid[sl] = 0x7fffffff; }

    int cur = 0;
    stage(0, 0, 0);
    for (int kt = 0; kt < NKT; kt++) {
        f32x4 acc[4][4];
        #pragma unroll
        for (int i = 0; i < 4; i++)
            #pragma unroll
            for (int j = 0; j < 4; j++) acc[i][j] = (f32x4)0.0f;

        for (int it = 0; it < 4; it++) {
            __syncthreads();                  // buf[cur] staging complete
            int nit = it + 1, nkt = kt;
            if (nit == 4) { nit = 0; nkt++; }
            if (nkt < NKT) stage(nkt, nit, cur ^ 1);   // prefetch overlaps MFMA
            unsigned char* base = smem8 + cur * 32768;
            #pragma unroll
            for (int s2 = 0; s2 < 2; s2++) {
                const int sw = ((((s2 << 2) | quad) ^ c7) << 4);
                bf16x8 af[4], bfr[4];
                #pragma unroll
                for (int i = 0; i < 4; i++)
                    af[i] = *(const bf16x8*)(base + (wm * 64 + i * 16 + c) * 128 + sw);
                #pragma unroll
                for (int j = 0; j < 4; j++)
                    bfr[j] = *(const bf16x8*)(base + 16384 + (wn * 64 + j * 16 + c) * 128 + sw);
                #pragma unroll
                for (int i = 0; i < 4; i++)
                    #pragma unroll
                    for (int j = 0; j < 4; j++)
                        acc[i][j] = __builtin_amdgcn_mfma_f32_16x16x32_bf16(af[i], bfr[j], acc[i][j], 0, 0, 0);
            }
            cur ^= 1;
        }
        // per-tile register epilogue (k ascending -> strict <, first idx)
        const int ktk = kbase + kt * 128;
        #pragma unroll
        for (int j = 0; j < 4; j++) {
            const int kk = ktk + wn * 64 + j * 16 + c;
            const float c2v = c2g[kk];
            #pragma unroll
            for (int i = 0; i < 4; i++)
                #pragma unroll
                for (int r = 0; r < 4; r++) {
                    float sc = fmaf(-2.0f, acc[i][j][r], c2v);
                    int sl = i * 4 + r;
                    if (sc < bm1[sl]) { bm2[sl] = bm1[sl]; bm1[sl] = sc; bid[sl] = kk; }
                    else if (sc < bm2[sl]) bm2[sl] = sc;
                }
        }
    }

    // once-per-block reduction: butterfly over the 16 c-lanes (same quad)
    #pragma unroll
    for (int mask = 1; mask <= 8; mask <<= 1)
        #pragma unroll
        for (int sl = 0; sl < 16; sl++) {
            float o1 = __shfl_xor(bm1[sl], mask, 64);
            float o2 = __shfl_xor(bm2[sl], mask, 64);
            int   oi = __shfl_xor(bid[sl], mask, 64);
            merge3(bm1[sl], bm2[sl], bid[sl], o1, o2, oi);
        }
    if (c == 0 && wn == 0) {
        #pragma unroll
        for (int i = 0; i < 4; i++)
            #pragma unroll
            for (int r = 0; r < 4; r++) {
                int ml = wm * 64 + i * 16 + quad * 4 + r, sl = i * 4 + r;
                redm1[ml] = bm1[sl]; redm2[ml] = bm2[sl]; redi[ml] = bid[sl];
            }
    }
    __syncthreads();
    if (c == 0 && wn == 1) {
        #pragma unroll
        for (int i = 0; i < 4; i++)
            #pragma unroll
            for (int r = 0; r < 4; r++) {
                int ml = wm * 64 + i * 16 + quad * 4 + r, sl = i * 4 + r;
                merge3(bm1[sl], bm2[sl], bid[sl], redm1[ml], redm2[ml], redi[ml]);
                pmx[(size_t)sp * NROWS + n0 + ml] =
                    make_float4(bm1[sl], bm2[sl], __int_as_float(bid[sl]), 0.f);
            }
    }
}

// ---------------- reduce 4 k-splits; flag ambiguous rows ----------------
__global__ void k_reduce2(const float4* __restrict__ pmx, int* __restrict__ widx,
                          int* __restrict__ cnt, int* __restrict__ list,
                          float* __restrict__ out) {
    int n = blockIdx.x * 256 + threadIdx.x;
    float a1 = FLT_MAX, a2 = FLT_MAX; int ai = 0x7fffffff;
    #pragma unroll
    for (int s = 0; s < FSPLIT; s++) {
        float4 p = pmx[(size_t)s * NROWS + n];
        merge3(a1, a2, ai, p.x, p.y, __float_as_int(p.z));
    }
    widx[n] = ai;
    out[OFF_IDX + n] = (float)ai;
    if (a2 - a1 < TAU) { int pos = atomicAdd(cnt, 1); list[pos] = n; }
}

// -------- exact np-pipeline rescue: Round-3 k_exact on compacted rows -------
// 32 flagged rows per group x 8 k-splits of 1024 codes. LDS-tiled codebook
// (32-row reuse per staged byte), d-ascending fmaf chain, (z2-2e)+c2, strict <.
__global__ __launch_bounds__(256) void k_rescuex(
        const float* __restrict__ z, const float* __restrict__ cb,
        const float* __restrict__ c2, const float* __restrict__ z2,
        const int* __restrict__ cnt, const int* __restrict__ list,
        float2* __restrict__ pr) {
    __shared__ float zs[D][MT];       // 32 KB (aliased for reduce at end)
    __shared__ float cs[DC][KT + 4];
    __shared__ int   ls[MT];
    __shared__ float z2sh[MT];
    const int tid = threadIdx.x;
    const int tx = tid & 31, ty = tid >> 5;
    const int grp = blockIdx.x >> 3, sp = blockIdx.x & 7;
    const int cntv = *cnt;
    const int base = grp * MT;
    if (base >= cntv) return;
    const int nr = min(MT, cntv - base);
    const int kbase = sp * (K / RSPLIT);

    if (tid < MT) {
        int pos = base + ((tid < nr) ? tid : (nr - 1));
        int n = list[pos];
        ls[tid] = n;
        z2sh[tid] = z2[n];
    }
    __syncthreads();
    for (int i = tid; i < D * MT; i += 256) {     // gather scattered z rows
        int d = i >> 5, r = i & 31;
        int n = ls[r];
        zs[d][r] = z[((size_t)((n >> 11) * CH + d)) * T + (n & 2047)];
    }
    float z2r[4];
    #pragma unroll
    for (int i = 0; i < 4; i++) z2r[i] = z2sh[ty * 4 + i];

    float m1[4]; int bi[4];
    #pragma unroll
    for (int i = 0; i < 4; i++) { m1[i] = FLT_MAX; bi[i] = 0x7fffffff; }
    for (int ktt = 0; ktt < K / RSPLIT; ktt += KT) {
        const int k0 = kbase + ktt;
        float acc[4][4] = {};
        for (int dc = 0; dc < D; dc += DC) {
            __syncthreads();
            {
                int kl = tid & 127, half = tid >> 7;
                const float4* src = (const float4*)(cb + (size_t)(k0 + kl) * D + dc + half * 16);
                #pragma unroll
                for (int j = 0; j < 4; j++) {
                    float4 v = src[j];
                    int dl = half * 16 + j * 4;
                    cs[dl + 0][kl] = v.x; cs[dl + 1][kl] = v.y;
                    cs[dl + 2][kl] = v.z; cs[dl + 3][kl] = v.w;
                }
            }
            __syncthreads();
            #pragma unroll 8
            for (int d = 0; d < DC; d++) {
                const float4 zf = *(const float4*)&zs[dc + d][ty * 4];
                const float4 cf = *(const float4*)&cs[d][tx * 4];
                const float za[4] = {zf.x, zf.y, zf.z, zf.w};
                const float ca[4] = {cf.x, cf.y, cf.z, cf.w};
                #pragma unroll
                for (int i = 0; i < 4; i++)
                    #pragma unroll
                    for (int j = 0; j < 4; j++)
                        acc[i][j] = fmaf(za[i], ca[j], acc[i][j]);
            }
        }
        #pragma unroll
        for (int j = 0; j < 4; j++) {
            int kk = k0 + tx * 4 + j;
            float c2v = c2[kk];
            #pragma unroll
            for (int i = 0; i < 4; i++) {
                float tpre = z2r[i] - 2.0f * acc[i][j];   // np combine order
                float s = tpre + c2v;
                if (s < m1[i]) { m1[i] = s; bi[i] = kk; } // strict <: first idx
            }
        }
    }
    __syncthreads();
    float* rm1 = (float*)zs;
    int*   rix = (int*)(rm1 + MT * 32);
    #pragma unroll
    for (int i = 0; i < 4; i++) {
        int slot = (ty * 4 + i) * 32 + tx;
        rm1[slot] = m1[i]; rix[slot] = bi[i];
    }
    __syncthreads();
    if (tid < MT) {
        float a1 = FLT_MAX; int ai = 0x7fffffff;
        for (int t = 0; t < 32; t++) {
            float b1 = rm1[tid * 32 + t]; int bidx = rix[tid * 32 + t];
            if (b1 < a1 || (b1 == a1 && bidx < ai)) { a1 = b1; ai = bidx; }
        }
        if (tid < nr)
            pr[(size_t)sp * NROWS + base + tid] = make_float2(a1, __int_as_float(ai));
    }
}

// -------- merge rescue splits (deterministic, split-ascending = k-asc) ------
__global__ void k_unpack(const float2* __restrict__ pr, const int* __restrict__ cnt,
                         const int* __restrict__ list, int* __restrict__ widx,
                         float* __restrict__ out) {
    int pos = blockIdx.x * 256 + threadIdx.x;
    if (pos >= *cnt) return;
    float a1 = FLT_MAX; int ai = 0x7fffffff;
    #pragma unroll
    for (int s = 0; s < RSPLIT; s++) {
        float2 p = pr[(size_t)s * NROWS + pos];
        float v = p.x; int ix = __float_as_int(p.y);
        if (v < a1 || (v == a1 && ix < ai)) { a1 = v; ai = ix; }
    }
    int n = list[pos];
    widx[n] = ai;
    out[OFF_IDX + n] = (float)ai;
}

// ---------------- fallback exact fp32 GEMM-argmin (Round-3, passing) --------
__global__ __launch_bounds__(256) void k_exact(
        const float* __restrict__ z, const float* __restrict__ cb,
        const float* __restrict__ c2, const float* __restrict__ z2,
        float2* __restrict__ part) {
    __shared__ float zs[D][MT];
    __shared__ float cs[DC][KT + 4];
    const int tid = threadIdx.x;
    const int tx = tid & 31, ty = tid >> 5;
    const int n0 = blockIdx.x * MT;
    const int bb = n0 >> 11, t0 = n0 & 2047;
    const int kbase = blockIdx.y * (K / NSPLIT);
    for (int i = tid; i < D * (MT / 4); i += 256) {
        int d = i >> 3, tg = i & 7;
        float4 v = *(const float4*)(z + ((size_t)(bb * CH + d)) * T + t0 + tg * 4);
        *(float4*)&zs[d][tg * 4] = v;
    }
    float z2r[4];
    #pragma unroll
    for (int i = 0; i < 4; i++) z2r[i] = z2[n0 + ty * 4 + i];
    float m1[4]; int bi[4];
    #pragma unroll
    for (int i = 0; i < 4; i++) { m1[i] = FLT_MAX; bi[i] = 0x7fffffff; }
    for (int ktt = 0; ktt < K / NSPLIT; ktt += KT) {
        const int k0 = kbase + ktt;
        float acc[4][4] = {};
        for (int dc = 0; dc < D; dc += DC) {
            __syncthreads();
            {
                int kl = tid & 127, half = tid >> 7;
                const float4* src = (const float4*)(cb + (size_t)(k0 + kl) * D + dc + half * 16);
                #pragma unroll
                for (int j = 0; j < 4; j++) {
                    float4 v = src[j];
                    int dl = half * 16 + j * 4;
                    cs[dl + 0][kl] = v.x; cs[dl + 1][kl] = v.y;
                    cs[dl + 2][kl] = v.z; cs[dl + 3][kl] = v.w;
                }
            }
            __syncthreads();
            #pragma unroll 8
            for (int d = 0; d < DC; d++) {
                const float4 zf = *(const float4*)&zs[dc + d][ty * 4];
                const float4 cf = *(const float4*)&cs[d][tx * 4];
                const float za[4] = {zf.x, zf.y, zf.z, zf.w};
                const float ca[4] = {cf.x, cf.y, cf.z, cf.w};
                #pragma unroll
                for (int i = 0; i < 4; i++)
                    #pragma unroll
                    for (int j = 0; j < 4; j++)
                        acc[i][j] = fmaf(za[i], ca[j], acc[i][j]);
            }
        }
        #pragma unroll
        for (int j = 0; j < 4; j++) {
            int kk = k0 + tx * 4 + j;
            float c2v = c2[kk];
            #pragma unroll
            for (int i = 0; i < 4; i++) {
                float tpre = z2r[i] - 2.0f * acc[i][j];
                float s = tpre + c2v;
                if (s < m1[i]) { m1[i] = s; bi[i] = kk; }
            }
        }
    }
    __syncthreads();
    float* rm1 = (float*)zs;
    int*   rix = (int*)(rm1 + MT * 32);
    #pragma unroll
    for (int i = 0; i < 4; i++) {
        int slot = (ty * 4 + i) * 32 + tx;
        rm1[slot] = m1[i]; rix[slot] = bi[i];
    }
    __syncthreads();
    if (tid < MT) {
        float a1 = FLT_MAX; int ai = 0x7fffffff;
        for (int t = 0; t < 32; t++) {
            float b1 = rm1[tid * 32 + t]; int bidx = rix[tid * 32 + t];
            if (b1 < a1 || (b1 == a1 && bidx < ai)) { a1 = b1; ai = bidx; }
        }
        part[(size_t)(n0 + tid) * NSPLIT + blockIdx.y] = make_float2(a1, __int_as_float(ai));
    }
}

__global__ void k_reduce(const float2* __restrict__ part, int* __restrict__ widx,
                         float* __restrict__ out) {
    int n = blockIdx.x * 256 + threadIdx.x;
    float a1 = FLT_MAX; int ai = 0x7fffffff;
    #pragma unroll
    for (int s = 0; s < NSPLIT; s++) {
        float2 p = part[(size_t)n * NSPLIT + s];
        float b1 = p.x; int bidx = __float_as_int(p.y);
        if (b1 < a1 || (b1 == a1 && bidx < ai)) { a1 = b1; ai = bidx; }
    }
    widx[n] = ai;
    out[OFF_IDX + n] = (float)ai;
}

// ------------- epilogue: gather z_q + loss partials ----------------
__global__ __launch_bounds__(256) void k_episem(
        const float* __restrict__ z, const float* __restrict__ cb,
        const int* __restrict__ widx, float* __restrict__ out, double* __restrict__ lossp) {
    __shared__ int qidx[32];
    __shared__ float qs[32][260];
    __shared__ double wsum[4];
    const int tid = threadIdx.x;
    const int bb = blockIdx.x >> 6;
    const int t0 = (blockIdx.x & 63) * 32;
    if (tid < 32) qidx[tid] = widx[bb * T + t0 + tid];
    __syncthreads();
    for (int i = tid; i < 32 * 64; i += 256) {
        int tl = i >> 6, lanee = i & 63;
        float4 v = *(const float4*)(cb + (size_t)qidx[tl] * D + lanee * 4);
        *(float4*)&qs[tl][lanee * 4] = v;
    }
    __syncthreads();
    double ls = 0.0;
    for (int it = 0; it < 32; it++) {
        int d = it * 8 + (tid >> 5);
        int tl = tid & 31;
        size_t ga = ((size_t)(bb * CH + d)) * T + t0 + tl;
        float q = qs[tl][d];
        float e = q - z[ga];
        out[ga] = q;
        ls += (double)e * (double)e;
    }
    #pragma unroll
    for (int off = 32; off; off >>= 1) ls += __shfl_down(ls, off, 64);
    if ((tid & 63) == 0) wsum[tid >> 6] = ls;
    __syncthreads();
    if (tid == 0) lossp[blockIdx.x] = wsum[0] + wsum[1] + wsum[2] + wsum[3];
}

// ------------- epilogue: ac path + fused loss finalize (block 0) -----------
__global__ void k_epiac(const float* __restrict__ z, const double* __restrict__ lossp,
                        float* __restrict__ out) {
    __shared__ double sm[256];
    int i = (blockIdx.x * 256 + threadIdx.x) * 4;   // grid exact: no early return
    int b = i / (DAC * T);
    int r = i % (DAC * T);
    int d = r / T, t = r % T;
    size_t zoff = ((size_t)(b * CH + 256 + d)) * T + t;
    float4 v = *(const float4*)(z + zoff);
    float r0, r1, r2, r3;
    {
        float t0 = (float)tanh((double)v.x); r0 = rintf(t0 * 10.0f);
        float t1 = (float)tanh((double)v.y); r1 = rintf(t1 * 10.0f);
        float t2 = (float)tanh((double)v.z); r2 = rintf(t2 * 10.0f);
        float t3 = (float)tanh((double)v.w); r3 = rintf(t3 * 10.0f);
    }
    *(float4*)(out + zoff) = make_float4(r0, r1, r2, r3);
    size_t co = OFF_CODES + (size_t)(b * DAC + d) * T + t;
    *(float4*)(out + co) = make_float4(r0 + 10.0f, r1 + 10.0f, r2 + 10.0f, r3 + 10.0f);
    size_t ao = OFF_ACQ + (size_t)(b * DAC + d) * T + t;
    out[ao + 0] = r0; out[ao + 1] = r1; out[ao + 2] = r2; out[ao + 3] = r3;
    if (blockIdx.x == 0) {
        int tid = threadIdx.x;
        sm[tid] = lossp[tid] + lossp[tid + 256];
        __syncthreads();
        for (int off = 128; off; off >>= 1) {
            if (tid < off) sm[tid] += sm[tid + off];
            __syncthreads();
        }
        if (tid == 0) out[OFF_LOSS] = (float)(1.1 * sm[0] / (double)(BQ * D * T));
    }
}

extern "C" void kernel_launch(void* const* d_in, const int* in_sizes, int n_in,
                              void* d_out, int out_size, void* d_ws, size_t ws_size,
                              hipStream_t stream) {
    const float* z  = (const float*)d_in[0];
    const float* cb = (const float*)d_in[1];
    float* out = (float*)d_out;
    char* ws = (char*)d_ws;

    if (ws_size >= (size_t)WN_NEED) {
        float*  c2    = (float*)(ws + WN_C2);
        float*  z2    = (float*)(ws + WN_Z2);
        int*    cnt   = (int*)(ws + WN_CNT);
        int*    list  = (int*)(ws + WN_LIST);
        double* lossp = (double*)(ws + WN_LOSS);
        int*    widx  = (int*)(ws + WN_WIDX);
        float4* pmx   = (float4*)(ws + WN_PMX);
        unsigned short* Az = (unsigned short*)(ws + WN_AZ);
        unsigned short* Bc = (unsigned short*)(ws + WN_BC);
        float2* pr    = (float2*)(ws + WN_PR);

        hipLaunchKernelGGL(k_prepc,   dim3(K / 4),        dim3(256), 0, stream, cb, Bc, c2, cnt);
        hipLaunchKernelGGL(k_prepz,   dim3(512),          dim3(256), 0, stream, z, Az, z2);
        hipLaunchKernelGGL(k_fast,    dim3(128 * FSPLIT), dim3(256), 0, stream, Az, Bc, c2, pmx);
        hipLaunchKernelGGL(k_reduce2, dim3(NROWS / 256),  dim3(256), 0, stream, pmx, widx, cnt, list, out);
        hipLaunchKernelGGL(k_rescuex, dim3((NROWS / MT) * RSPLIT), dim3(256), 0, stream,
                           z, cb, c2, z2, cnt, list, pr);
        hipLaunchKernelGGL(k_unpack,  dim3(NROWS / 256),  dim3(256), 0, stream, pr, cnt, list, widx, out);
        hipLaunchKernelGGL(k_episem,  dim3(BQ * (T / 32)), dim3(256), 0, stream, z, cb, widx, out, lossp);
        hipLaunchKernelGGL(k_epiac,   dim3(BQ * DAC * T / 1024), dim3(256), 0, stream, z, lossp, out);
    } else {
        float*  c2    = (float*)(ws + WS_C2);
        float*  z2    = (float*)(ws + WS_Z2);
        float2* part  = (float2*)(ws + WS_PART);
        int*    widx  = (int*)(ws + WS_IDX);
        double* lossp = (double*)(ws + WS_LOSS);
        hipLaunchKernelGGL(k_c2pw,   dim3(K / 256),            dim3(256), 0, stream, cb, c2);
        hipLaunchKernelGGL(k_z2pw,   dim3(NROWS / 256),        dim3(256), 0, stream, z, z2);
        hipLaunchKernelGGL(k_exact,  dim3(NROWS / MT, NSPLIT), dim3(256), 0, stream, z, cb, c2, z2, part);
        hipLaunchKernelGGL(k_reduce, dim3(NROWS / 256),        dim3(256), 0, stream, part, widx, out);
        hipLaunchKernelGGL(k_episem, dim3(BQ * (T / 32)),      dim3(256), 0, stream, z, cb, widx, out, lossp);
        hipLaunchKernelGGL(k_epiac,  dim3(BQ * DAC * T / 1024), dim3(256), 0, stream, z, lossp, out);
    }
}